// Round 5
// baseline (4296.518 us; speedup 1.0000x reference)
//
#include <hip/hip_runtime.h>
#include <hip/hip_bf16.h>
#include <stdint.h>

// Sizes (fixed by the problem)
#define BATCH 64
#define SEQ   4096
#define CIN   128
#define F     64      // LATENT
#define GATES 256     // 4*F
#define NF    10
#define NCHUNK (SEQ / 16)

// ---------------- ws layout (requires ws_size >= 67,108,864 B; 100.7MB verified OK round 2) ----------------
// cv : f32 [B][S][F]  conv stack output  67,108,864 B @ 0
#define CV_OFF 0ull

typedef float f32x2 __attribute__((ext_vector_type(2)));

static __device__ __forceinline__ float sigm(float x) {
  return 1.0f / (1.0f + __expf(-x));
}
static __device__ __forceinline__ float tanh_f(float x) {
  float e = __expf(2.0f * x);           // graceful at +-inf
  return 1.0f - 2.0f / (e + 1.0f);
}

// ---------------- fused 3-stage conv1d (k=3, SAME) + ReLU ----------------
// One WG computes 64 output positions for one batch. Halo rows recomputed;
// rows whose ABSOLUTE position is outside [0,SEQ) forced to 0 (per-layer pad).
// LDS row strides padded (132 / 68 floats) to break bank-conflict alignment.
template<int NIN, int LDI, int LDO, int NROWS, bool TOG>
static __device__ __forceinline__ void conv_stage(
    const float* in, const float* __restrict__ w, const float* __restrict__ bias,
    float* out, float* gout, int gbase, int tbase)
{
  const int tid = threadIdx.x;
  const int cb = (tid & 15) << 2;   // out-channel base (4 per thread)
  const int pg = tid >> 4;          // row phase 0..15
  constexpr int M = (NROWS + 15) / 16;
  float acc[M][4];
#pragma unroll
  for (int m = 0; m < M; ++m) { acc[m][0] = acc[m][1] = acc[m][2] = acc[m][3] = 0.f; }
#pragma unroll 1
  for (int cc = 0; cc < NIN; cc += 8) {
    float wr[3][8][4];
#pragma unroll
    for (int k = 0; k < 3; ++k)
#pragma unroll
      for (int ci = 0; ci < 8; ++ci) {
        const float4 t = *(const float4*)&w[(k * NIN + cc + ci) * F + cb];
        wr[k][ci][0] = t.x; wr[k][ci][1] = t.y; wr[k][ci][2] = t.z; wr[k][ci][3] = t.w;
      }
#pragma unroll
    for (int m = 0; m < M; ++m) {
      const int r = pg + 16 * m;
      if ((M * 16 == NROWS) || (r < NROWS)) {
#pragma unroll
        for (int k = 0; k < 3; ++k) {
          const float* row = &in[(r + k) * LDI + cc];
          const float4 a  = *(const float4*)&row[0];
          const float4 b4 = *(const float4*)&row[4];
          const float xv[8] = {a.x, a.y, a.z, a.w, b4.x, b4.y, b4.z, b4.w};
#pragma unroll
          for (int ci = 0; ci < 8; ++ci) {
            acc[m][0] += xv[ci] * wr[k][ci][0];
            acc[m][1] += xv[ci] * wr[k][ci][1];
            acc[m][2] += xv[ci] * wr[k][ci][2];
            acc[m][3] += xv[ci] * wr[k][ci][3];
          }
        }
      }
    }
  }
  const float4 bv = *(const float4*)&bias[cb];
#pragma unroll
  for (int m = 0; m < M; ++m) {
    const int r = pg + 16 * m;
    if ((M * 16 == NROWS) || (r < NROWS)) {
      const bool ok = (unsigned)(tbase + r) < (unsigned)SEQ;  // per-layer zero padding
      const float o0 = ok ? fmaxf(acc[m][0] + bv.x, 0.f) : 0.f;
      const float o1 = ok ? fmaxf(acc[m][1] + bv.y, 0.f) : 0.f;
      const float o2 = ok ? fmaxf(acc[m][2] + bv.z, 0.f) : 0.f;
      const float o3 = ok ? fmaxf(acc[m][3] + bv.w, 0.f) : 0.f;
      if (TOG) {
        *(float4*)&gout[gbase + r * F + cb] = make_float4(o0, o1, o2, o3);
      } else {
        *(float4*)&out[r * LDO + cb] = make_float4(o0, o1, o2, o3);
      }
    }
  }
}

__global__ __launch_bounds__(256, 2) void conv_fused(
    const float* __restrict__ x,
    const float* __restrict__ w0, const float* __restrict__ b0,
    const float* __restrict__ w1, const float* __restrict__ b1,
    const float* __restrict__ w2, const float* __restrict__ b2,
    float* __restrict__ cv)
{
  __shared__ __align__(16) float xs[70 * 132];   // x[t0-3 .. t0+66], stride 132
  __shared__ __align__(16) float y0s[68 * 68];   // y0[t0-2 .. t0+65], stride 68
  __shared__ __align__(16) float y1s[66 * 68];   // y1[t0-1 .. t0+64], stride 68
  const int wg  = blockIdx.x;
  const int b   = wg >> 6;
  const int t0  = (wg & 63) << 6;
  const int tid = threadIdx.x;

  const float* xb = x + (size_t)b * SEQ * CIN;
  for (int i = tid; i < 70 * (CIN / 4); i += 256) {
    const int r  = i >> 5;
    const int c4 = (i & 31) << 2;
    const int t  = t0 - 3 + r;
    float4 v = make_float4(0.f, 0.f, 0.f, 0.f);
    if ((unsigned)t < (unsigned)SEQ) v = *(const float4*)&xb[(size_t)t * CIN + c4];
    *(float4*)&xs[r * 132 + c4] = v;
  }
  __syncthreads();
  conv_stage<CIN, 132, 68, 68, false>(xs, w0, b0, y0s, nullptr, 0, t0 - 2);
  __syncthreads();
  conv_stage<F, 68, 68, 66, false>(y0s, w1, b1, y1s, nullptr, 0, t0 - 1);
  __syncthreads();
  conv_stage<F, 68, 64, 64, true>(y1s, w2, b2, nullptr, cv, (b * SEQ + t0) * F, t0);
}

// ---------------- fused two-layer persistent LSTM scan ----------------
// Grid = 64 WGs (one per batch) x 512 threads (8 waves). Software pipeline:
// waves 0-3 compute layer-0 gates for tick t while waves 4-7 compute layer-1
// gates for tick t-1 (layer 1 lags one tick). All communication through LDS:
//   hh  = h0 state (written by wave 0 phase B at tick t, read next tick by
//         layer 0 as its h and by layer 1 as its x)
//   hl1 = h1 state (wave 4)
// No global ring, no flags, no atomics. 2 barriers per tick.
// Thread (q = tid&63, kc = (tid>>6)&3, layer = tid>>8): computes gates
// {q,q+64,q+128,q+192} partial over k in [16kc,16kc+16). Weights as f32x2
// k-pairs -> v_pk_fma_f32. Bias folded into kc==0 acc init.
__global__ __launch_bounds__(512, 1) void lstm_scan(
    const float* __restrict__ cv,
    const float* __restrict__ Wx0, const float* __restrict__ Wh0, const float* __restrict__ bl0,
    const float* __restrict__ Wx1, const float* __restrict__ Wh1, const float* __restrict__ bl1,
    const float* __restrict__ dw, const float* __restrict__ db,
    float* __restrict__ out)
{
  const int b   = blockIdx.x;
  const int tid = threadIdx.x;
  const int q   = tid & 63;
  const int w   = tid >> 6;                 // wave 0..7
  const int kc  = w & 3;                    // k-chunk within layer
  const bool lay0 = (__builtin_amdgcn_readfirstlane(w) < 4);

  __shared__ __align__(16) float xch[16][F];       // conv chunk (16 ticks)
  __shared__ __align__(16) float hh[F];            // h0 state
  __shared__ __align__(16) float hl1[F];           // h1 state
  __shared__ __align__(16) f32x2 parts2[8][2][F];  // [wave][(g0,g1)|(g2,g3)][q]
  __shared__ __align__(16) float csave[F];

  const float* Wx = lay0 ? Wx0 : Wx1;
  const float* Wh = lay0 ? Wh0 : Wh1;
  const float* bb = lay0 ? bl0 : bl1;

  // per-thread weight slices as k-pairs
  f32x2 wx2[4][8], wh2[4][8];
#pragma unroll
  for (int g = 0; g < 4; ++g)
#pragma unroll
    for (int p = 0; p < 8; ++p) {
      const int k = (kc << 4) + (p << 1);
      const int j = q + (g << 6);
      wx2[g][p] = f32x2{Wx[k * GATES + j], Wx[(k + 1) * GATES + j]};
      wh2[g][p] = f32x2{Wh[k * GATES + j], Wh[(k + 1) * GATES + j]};
    }
  float biasv[4];
#pragma unroll
  for (int g = 0; g < 4; ++g) biasv[g] = (kc == 0) ? bb[q + (g << 6)] : 0.f;
  if (tid < F) { hh[tid] = 0.f; hl1[tid] = 0.f; }
  float creg = 0.f;                        // c0 on wave 0 lanes, c1 on wave 4 lanes
  __syncthreads();

  const float* xsrc = cv + (size_t)b * SEQ * F;
  float4 xreg;                             // staged next conv chunk (waves 0-3)
  if (tid < 256) xreg = *(const float4*)&xsrc[tid << 2];

#pragma unroll 1
  for (int c = 0; c < NCHUNK; ++c) {
    // ---- stage conv chunk into LDS (1024 floats, waves 0-3) ----
    if (tid < 256) {
      ((float4*)&xch[0][0])[tid] = xreg;   // compiler inserts vmcnt wait
      if (c + 1 < NCHUNK)
        xreg = *(const float4*)&xsrc[(c + 1) * 1024 + (tid << 2)];  // prefetch
    }
    __syncthreads();

    // preload x pairs for tick 0 (layer 0 only)
    f32x2 xv2[8];
    if (lay0) {
      const float4* xp4 = (const float4*)&xch[0][kc << 4];
#pragma unroll
      for (int u = 0; u < 4; ++u) {
        const float4 a = xp4[u];
        xv2[2 * u]     = f32x2{a.x, a.y};
        xv2[2 * u + 1] = f32x2{a.z, a.w};
      }
    }

#pragma unroll 1
    for (int it = 0; it < 16; ++it) {
      // ---- Phase A: partial gates for both layers ----
      // L0: gates = xch[it]*Wx0 + h0*Wh0 ; L1: gates = h0*Wx1 + h1*Wh1
      f32x2 acc2[4];
#pragma unroll
      for (int g = 0; g < 4; ++g) acc2[g] = f32x2{biasv[g], 0.f};

      float4 h0r[4];
      {
        const float4* hp4 = (const float4*)&hh[kc << 4];
#pragma unroll
        for (int u = 0; u < 4; ++u) h0r[u] = hp4[u];
      }
      f32x2 pv[8], qv[8];                  // pv multiplies Wx, qv multiplies Wh
      if (lay0) {
#pragma unroll
        for (int p = 0; p < 8; ++p) pv[p] = xv2[p];
#pragma unroll
        for (int u = 0; u < 4; ++u) {
          qv[2 * u]     = f32x2{h0r[u].x, h0r[u].y};
          qv[2 * u + 1] = f32x2{h0r[u].z, h0r[u].w};
        }
      } else {
        float4 h1r[4];
        const float4* gp4 = (const float4*)&hl1[kc << 4];
#pragma unroll
        for (int u = 0; u < 4; ++u) h1r[u] = gp4[u];
#pragma unroll
        for (int u = 0; u < 4; ++u) {
          pv[2 * u]     = f32x2{h0r[u].x, h0r[u].y};
          pv[2 * u + 1] = f32x2{h0r[u].z, h0r[u].w};
          qv[2 * u]     = f32x2{h1r[u].x, h1r[u].y};
          qv[2 * u + 1] = f32x2{h1r[u].z, h1r[u].w};
        }
      }
#pragma unroll
      for (int p = 0; p < 8; ++p) {
        acc2[0] += pv[p] * wx2[0][p]; acc2[1] += pv[p] * wx2[1][p];
        acc2[2] += pv[p] * wx2[2][p]; acc2[3] += pv[p] * wx2[3][p];
      }
#pragma unroll
      for (int p = 0; p < 8; ++p) {
        acc2[0] += qv[p] * wh2[0][p]; acc2[1] += qv[p] * wh2[1][p];
        acc2[2] += qv[p] * wh2[2][p]; acc2[3] += qv[p] * wh2[3][p];
      }
      parts2[w][0][q] = f32x2{acc2[0].x + acc2[0].y, acc2[1].x + acc2[1].y};
      parts2[w][1][q] = f32x2{acc2[2].x + acc2[2].y, acc2[3].x + acc2[3].y};
      // prefetch next tick's x pairs (chunk-stable)
      if (lay0 && it < 15) {
        const float4* xp4 = (const float4*)&xch[it + 1][kc << 4];
#pragma unroll
        for (int u = 0; u < 4; ++u) {
          const float4 a = xp4[u];
          xv2[2 * u]     = f32x2{a.x, a.y};
          xv2[2 * u + 1] = f32x2{a.z, a.w};
        }
      }
      __syncthreads();
      // ---- Phase B: state update (wave 0 = layer 0 tick t; wave 4 = layer 1 tick t-1) ----
      if (kc == 0) {
        const bool active = lay0 | ((c | it) != 0);   // layer 1 idle at t==0
        if (active) {
          const f32x2 s01 = parts2[w][0][q] + parts2[w + 1][0][q] + parts2[w + 2][0][q] + parts2[w + 3][0][q];
          const f32x2 s23 = parts2[w][1][q] + parts2[w + 1][1][q] + parts2[w + 2][1][q] + parts2[w + 3][1][q];
          const float iv = sigm(s01.x);
          const float fv = sigm(s01.y);
          const float gv = tanh_f(s23.x);
          const float ov = sigm(s23.y);
          creg = fv * creg + iv * gv;
          const float hnew = ov * tanh_f(creg);
          if (lay0) hh[q] = hnew; else hl1[q] = hnew;
        }
      }
      __syncthreads();
    }
  }

  // ---- epilogue tick t=4096: layer 1 consumes h0[4095] ----
  {
    if (!lay0) {
      f32x2 acc2[4];
#pragma unroll
      for (int g = 0; g < 4; ++g) acc2[g] = f32x2{biasv[g], 0.f};
      float4 h0r[4], h1r[4];
      {
        const float4* hp4 = (const float4*)&hh[kc << 4];
        const float4* gp4 = (const float4*)&hl1[kc << 4];
#pragma unroll
        for (int u = 0; u < 4; ++u) { h0r[u] = hp4[u]; h1r[u] = gp4[u]; }
      }
      f32x2 pv[8], qv[8];
#pragma unroll
      for (int u = 0; u < 4; ++u) {
        pv[2 * u]     = f32x2{h0r[u].x, h0r[u].y};
        pv[2 * u + 1] = f32x2{h0r[u].z, h0r[u].w};
        qv[2 * u]     = f32x2{h1r[u].x, h1r[u].y};
        qv[2 * u + 1] = f32x2{h1r[u].z, h1r[u].w};
      }
#pragma unroll
      for (int p = 0; p < 8; ++p) {
        acc2[0] += pv[p] * wx2[0][p]; acc2[1] += pv[p] * wx2[1][p];
        acc2[2] += pv[p] * wx2[2][p]; acc2[3] += pv[p] * wx2[3][p];
        acc2[0] += qv[p] * wh2[0][p]; acc2[1] += qv[p] * wh2[1][p];
        acc2[2] += qv[p] * wh2[2][p]; acc2[3] += qv[p] * wh2[3][p];
      }
      parts2[w][0][q] = f32x2{acc2[0].x + acc2[0].y, acc2[1].x + acc2[1].y};
      parts2[w][1][q] = f32x2{acc2[2].x + acc2[2].y, acc2[3].x + acc2[3].y};
    }
    __syncthreads();
    if (w == 4) {
      const f32x2 s01 = parts2[4][0][q] + parts2[5][0][q] + parts2[6][0][q] + parts2[7][0][q];
      const f32x2 s23 = parts2[4][1][q] + parts2[5][1][q] + parts2[6][1][q] + parts2[7][1][q];
      const float iv = sigm(s01.x);
      const float fv = sigm(s01.y);
      const float gv = tanh_f(s23.x);
      creg = fv * creg + iv * gv;     // final c1; h not needed
      csave[q] = creg;
    }
    __syncthreads();
  }

  // ---- dense head from final c of layer 1 ----
  if (tid < NF) {
    float acc = db[tid];
#pragma unroll 1
    for (int f = 0; f < F; ++f) acc += csave[f] * dw[f * NF + tid];
    out[b * NF + tid] = acc;
  }
}

extern "C" void kernel_launch(void* const* d_in, const int* in_sizes, int n_in,
                              void* d_out, int out_size, void* d_ws, size_t ws_size,
                              hipStream_t stream) {
  const float* x   = (const float*)d_in[0];
  const float* w0  = (const float*)d_in[1];
  const float* b0  = (const float*)d_in[2];
  const float* w1  = (const float*)d_in[3];
  const float* b1  = (const float*)d_in[4];
  const float* w2  = (const float*)d_in[5];
  const float* b2  = (const float*)d_in[6];
  const float* Wx0 = (const float*)d_in[7];
  const float* Wh0 = (const float*)d_in[8];
  const float* bl0 = (const float*)d_in[9];
  const float* Wx1 = (const float*)d_in[10];
  const float* Wh1 = (const float*)d_in[11];
  const float* bl1 = (const float*)d_in[12];
  const float* dw  = (const float*)d_in[13];
  const float* db  = (const float*)d_in[14];
  float* out = (float*)d_out;

  float* cv = (float*)((char*)d_ws + CV_OFF);

  conv_fused<<<dim3(4096), dim3(256), 0, stream>>>(x, w0, b0, w1, b1, w2, b2, cv);
  lstm_scan<<<dim3(64), dim3(512), 0, stream>>>(cv,
                                                Wx0, Wh0, bl0, Wx1, Wh1, bl1,
                                                dw, db, out);
}

// Round 6
// 4007.270 us; speedup vs baseline: 1.0722x; 1.0722x over previous
//
#include <hip/hip_runtime.h>
#include <hip/hip_bf16.h>
#include <stdint.h>

// Sizes (fixed by the problem)
#define BATCH 64
#define SEQ   4096
#define CIN   128
#define F     64      // LATENT
#define GATES 256     // 4*F
#define NF    10
#define NSLOT 16      // h0 ring slots per batch (chunks of 16 ticks)
#define NCHUNK (SEQ / 16)

// ---------------- ws layout (requires ws_size >= 71,319,552 B; verified OK round 2) ----------------
// cv    : f32 [B][S][F]        conv stack output   67,108,864 B @ 0
// h0ring: f32 [B][NSLOT][16][F]                      4,194,304 B @ 67,108,864
// flags : prod u32/batch @128B (8KB), cons (8KB)       16,384 B @ 71,303,168
#define CV_OFF    0ull
#define RING_OFF  67108864ull
#define FLAGS_OFF 71303168ull

typedef float f32x2 __attribute__((ext_vector_type(2)));

// ---------------- fused 3-stage conv1d (k=3, SAME) + ReLU ----------------
// One WG computes 64 output positions for one batch. Halo rows recomputed;
// rows whose ABSOLUTE position is outside [0,SEQ) forced to 0 (per-layer pad).
// LDS strides padded (132/68). Inner loop packed as f32x2 (pairs over ci)
// -> v_pk_fma_f32, halving VALU issue vs scalar.
template<int NIN, int LDI, int LDO, int NROWS, bool TOG>
static __device__ __forceinline__ void conv_stage(
    const float* in, const float* __restrict__ w, const float* __restrict__ bias,
    float* out, float* gout, int gbase, int tbase)
{
  const int tid = threadIdx.x;
  const int cb = (tid & 15) << 2;   // out-channel base (4 per thread)
  const int pg = tid >> 4;          // row phase 0..15
  constexpr int M = (NROWS + 15) / 16;
  f32x2 acc2[M][4];
#pragma unroll
  for (int m = 0; m < M; ++m)
#pragma unroll
    for (int o = 0; o < 4; ++o) acc2[m][o] = f32x2{0.f, 0.f};
#pragma unroll 1
  for (int cc = 0; cc < NIN; cc += 8) {
    f32x2 wr2[3][4][4];   // [k][ci-pair][out]
#pragma unroll
    for (int k = 0; k < 3; ++k)
#pragma unroll
      for (int p = 0; p < 4; ++p) {
        const float4 t0 = *(const float4*)&w[(k * NIN + cc + 2 * p) * F + cb];
        const float4 t1 = *(const float4*)&w[(k * NIN + cc + 2 * p + 1) * F + cb];
        wr2[k][p][0] = f32x2{t0.x, t1.x};
        wr2[k][p][1] = f32x2{t0.y, t1.y};
        wr2[k][p][2] = f32x2{t0.z, t1.z};
        wr2[k][p][3] = f32x2{t0.w, t1.w};
      }
#pragma unroll
    for (int m = 0; m < M; ++m) {
      const int r = pg + 16 * m;
      if ((M * 16 == NROWS) || (r < NROWS)) {
#pragma unroll
        for (int k = 0; k < 3; ++k) {
          const float* row = &in[(r + k) * LDI + cc];
          const float4 a  = *(const float4*)&row[0];
          const float4 b4 = *(const float4*)&row[4];
          const f32x2 xp[4] = {{a.x, a.y}, {a.z, a.w}, {b4.x, b4.y}, {b4.z, b4.w}};
#pragma unroll
          for (int p = 0; p < 4; ++p) {
#pragma unroll
            for (int o = 0; o < 4; ++o)
              acc2[m][o] += xp[p] * wr2[k][p][o];
          }
        }
      }
    }
  }
  const float4 bv = *(const float4*)&bias[cb];
#pragma unroll
  for (int m = 0; m < M; ++m) {
    const int r = pg + 16 * m;
    if ((M * 16 == NROWS) || (r < NROWS)) {
      const bool ok = (unsigned)(tbase + r) < (unsigned)SEQ;  // per-layer zero padding
      const float o0 = ok ? fmaxf(acc2[m][0].x + acc2[m][0].y + bv.x, 0.f) : 0.f;
      const float o1 = ok ? fmaxf(acc2[m][1].x + acc2[m][1].y + bv.y, 0.f) : 0.f;
      const float o2 = ok ? fmaxf(acc2[m][2].x + acc2[m][2].y + bv.z, 0.f) : 0.f;
      const float o3 = ok ? fmaxf(acc2[m][3].x + acc2[m][3].y + bv.w, 0.f) : 0.f;
      if (TOG) {
        *(float4*)&gout[gbase + r * F + cb] = make_float4(o0, o1, o2, o3);
      } else {
        *(float4*)&out[r * LDO + cb] = make_float4(o0, o1, o2, o3);
      }
    }
  }
}

__global__ __launch_bounds__(256, 2) void conv_fused(
    const float* __restrict__ x,
    const float* __restrict__ w0, const float* __restrict__ b0,
    const float* __restrict__ w1, const float* __restrict__ b1,
    const float* __restrict__ w2, const float* __restrict__ b2,
    float* __restrict__ cv)
{
  __shared__ __align__(16) float xs[70 * 132];   // x[t0-3 .. t0+66], stride 132
  __shared__ __align__(16) float y0s[68 * 68];   // y0[t0-2 .. t0+65], stride 68
  __shared__ __align__(16) float y1s[66 * 68];   // y1[t0-1 .. t0+64], stride 68
  const int wg  = blockIdx.x;
  const int b   = wg >> 6;
  const int t0  = (wg & 63) << 6;
  const int tid = threadIdx.x;

  const float* xb = x + (size_t)b * SEQ * CIN;
  for (int i = tid; i < 70 * (CIN / 4); i += 256) {
    const int r  = i >> 5;
    const int c4 = (i & 31) << 2;
    const int t  = t0 - 3 + r;
    float4 v = make_float4(0.f, 0.f, 0.f, 0.f);
    if ((unsigned)t < (unsigned)SEQ) v = *(const float4*)&xb[(size_t)t * CIN + c4];
    *(float4*)&xs[r * 132 + c4] = v;
  }
  __syncthreads();
  conv_stage<CIN, 132, 68, 68, false>(xs, w0, b0, y0s, nullptr, 0, t0 - 2);
  __syncthreads();
  conv_stage<F, 68, 68, 66, false>(y0s, w1, b1, y1s, nullptr, 0, t0 - 1);
  __syncthreads();
  conv_stage<F, 68, 64, 64, true>(y1s, w2, b2, nullptr, cv, (b * SEQ + t0) * F, t0);
}

// ---------------- persistent LSTM scan (q-split, full-k in-lane) ----------------
// Grid = 128 WGs x 256 threads. WG<64: layer-0 producer (batch=wg); WG>=64:
// layer-1 consumer. Ring+flags handoff as round 2 (measured working).
// Thread (l=tid&63, w=tid>>6): qi=l>>2, gb=l&3, q=w*16+qi. Each lane computes
// ONE complete gate (q,gb) = full 64-k dot (weights in 128 VGPRs as f32x2
// pairs -> v_pk_fma_f32). No cross-wave reduction: activation in-lane
// (branchless, v_exp + v_rcp), gather i/f/g/o to the gb==0 owner lane via 3
// __shfl_down, c/h update in owner lane. h state double-buffered in LDS ->
// ONE __syncthreads per tick. h history in LDS, ring-flushed once per chunk.
__global__ __launch_bounds__(256, 1) void lstm_scan(
    const float* __restrict__ cv,
    float* __restrict__ ring, uint32_t* __restrict__ flags,
    const float* __restrict__ Wx0, const float* __restrict__ Wh0, const float* __restrict__ bl0,
    const float* __restrict__ Wx1, const float* __restrict__ Wh1, const float* __restrict__ bl1,
    const float* __restrict__ dw, const float* __restrict__ db,
    float* __restrict__ out)
{
  const int  wg   = blockIdx.x;
  const bool prod = (wg < BATCH);
  const int  b    = prod ? wg : (wg - BATCH);
  const int  tid  = threadIdx.x;
  const int  l    = tid & 63;
  const int  w    = tid >> 6;
  const int  qi   = l >> 2;
  const int  gb   = l & 3;          // 0=i 1=f 2=g(tanh) 3=o
  const int  q    = (w << 4) + qi;  // owned q (on gb==0 lanes)

  __shared__ __align__(16) float xch[16][F];   // input chunk (16 ticks)
  __shared__ __align__(16) float hl[2][F];     // h state, double-buffered
  __shared__ __align__(16) float hh[16][F];    // h history for chunk flush
  __shared__ __align__(16) float csave[F];

  const float* Wx = prod ? Wx0 : Wx1;
  const float* Wh = prod ? Wh0 : Wh1;
  const float* bb = prod ? bl0 : bl1;
  const int j = (gb << 6) + q;      // weight column for this lane's gate

  f32x2 wx2[32], wh2[32];
#pragma unroll
  for (int p = 0; p < 32; ++p) {
    wx2[p] = f32x2{Wx[(2 * p) * GATES + j], Wx[(2 * p + 1) * GATES + j]};
    wh2[p] = f32x2{Wh[(2 * p) * GATES + j], Wh[(2 * p + 1) * GATES + j]};
  }
  const float bias = bb[j];
  if (tid < F) { hl[0][tid] = 0.f; hl[1][tid] = 0.f; }
  float creg = 0.f;                 // c state lives in gb==0 lanes
  __syncthreads();

  const float* xsrc = cv + (size_t)b * SEQ * F;
  float* myring = ring + (size_t)b * NSLOT * 16 * F;
  uint32_t* prodflag = flags + b * 32;            // 128B stride
  uint32_t* consflag = flags + 2048 + b * 32;     // second 8KB region

  float4 xreg;                                    // producer: staged next chunk
  if (prod) xreg = *(const float4*)&xsrc[tid << 2];

#pragma unroll 1
  for (int c = 0; c < NCHUNK; ++c) {
    const int slot = c & (NSLOT - 1);
    // ---- stage chunk input into LDS (1024 floats, 4/thread) ----
    if (prod) {
      ((float4*)&xch[0][0])[tid] = xreg;          // vmcnt wait auto-inserted
      if (c + 1 < NCHUNK)
        xreg = *(const float4*)&xsrc[(c + 1) * 1024 + (tid << 2)];  // prefetch
    } else {
      while (__hip_atomic_load(prodflag, __ATOMIC_ACQUIRE, __HIP_MEMORY_SCOPE_AGENT) <= (uint32_t)c)
        __builtin_amdgcn_s_sleep(2);
      const float* src = myring + slot * 1024 + (tid << 2);
      float4 f4;
      f4.x = __hip_atomic_load(src + 0, __ATOMIC_RELAXED, __HIP_MEMORY_SCOPE_AGENT);
      f4.y = __hip_atomic_load(src + 1, __ATOMIC_RELAXED, __HIP_MEMORY_SCOPE_AGENT);
      f4.z = __hip_atomic_load(src + 2, __ATOMIC_RELAXED, __HIP_MEMORY_SCOPE_AGENT);
      f4.w = __hip_atomic_load(src + 3, __ATOMIC_RELAXED, __HIP_MEMORY_SCOPE_AGENT);
      ((float4*)&xch[0][0])[tid] = f4;
    }
    __syncthreads();
    if (!prod && tid == 0)
      __hip_atomic_store(consflag, (uint32_t)(c + 1),
                         __ATOMIC_RELEASE, __HIP_MEMORY_SCOPE_AGENT);

    // load x vector for tick 0 (all 64 values, broadcast reads)
    float4 xcur[16];
    {
      const float4* xp = (const float4*)&xch[0][0];
#pragma unroll
      for (int m = 0; m < 16; ++m) xcur[m] = xp[m];
    }

#pragma unroll 1
    for (int it = 0; it < 16; ++it) {
      const int rb = it & 1;                       // buffer holding h_{t-1}
      // issue all h reads (broadcast, conflict-free)
      float4 hq[16];
      {
        const float4* hp = (const float4*)&hl[rb][0];
#pragma unroll
        for (int m = 0; m < 16; ++m) hq[m] = hp[m];
      }
      // x-dot first (xcur already in regs) while h reads fly
      f32x2 a0{0.f, 0.f}, a1{0.f, 0.f}, a2{0.f, 0.f}, a3{0.f, 0.f};
#pragma unroll
      for (int m = 0; m < 16; ++m) {
        a0 += f32x2{xcur[m].x, xcur[m].y} * wx2[2 * m];
        a1 += f32x2{xcur[m].z, xcur[m].w} * wx2[2 * m + 1];
      }
#pragma unroll
      for (int m = 0; m < 16; ++m) {
        a2 += f32x2{hq[m].x, hq[m].y} * wh2[2 * m];
        a3 += f32x2{hq[m].z, hq[m].w} * wh2[2 * m + 1];
      }
      // prefetch next tick's x (chunk-stable; overlaps the tail)
      if (it < 15) {
        const float4* xp = (const float4*)&xch[it + 1][0];
#pragma unroll
        for (int m = 0; m < 16; ++m) xcur[m] = xp[m];
      }
      const float s = ((a0.x + a0.y) + (a1.x + a1.y)) +
                      ((a2.x + a2.y) + (a3.x + a3.y)) + bias;
      // branchless activation: sigm for i/f/o, tanh for g
      const bool isg = (gb == 2);
      const float aa = isg ? (-2.f * s) : (-s);
      const float e  = __expf(aa);
      const float rr = __builtin_amdgcn_rcpf(1.f + e);
      const float act = isg ? (2.f * rr - 1.f) : rr;
      // gather f,g,o to owner lane (gb==0); groups of 4 stay in one 16-lane row
      const float fv = __shfl_down(act, 1);
      const float gv = __shfl_down(act, 2);
      const float ov = __shfl_down(act, 3);
      if (gb == 0) {
        creg = fv * creg + act * gv;               // act == i on owner lanes
        const float e2 = __expf(-2.f * creg);
        const float th = 2.f * __builtin_amdgcn_rcpf(1.f + e2) - 1.f;
        const float hnew = ov * th;
        hl[rb ^ 1][q] = hnew;
        hh[it][q] = hnew;
      }
      __syncthreads();
    }

    // ---- producer: flush h chunk to ring ----
    if (prod) {
      while ((uint32_t)c >= NSLOT + __hip_atomic_load(consflag, __ATOMIC_ACQUIRE, __HIP_MEMORY_SCOPE_AGENT))
        __builtin_amdgcn_s_sleep(2);
      float* dst = myring + slot * 1024;
      *(float4*)&dst[tid << 2] = ((const float4*)&hh[0][0])[tid];
      __syncthreads();              // per-wave vmcnt drain before release
      if (tid == 0)
        __hip_atomic_store(prodflag, (uint32_t)(c + 1),
                           __ATOMIC_RELEASE, __HIP_MEMORY_SCOPE_AGENT);
    }
  }

  // ---- dense head from final c of layer 1 ----
  if (!prod) {
    if (gb == 0) csave[q] = creg;
    __syncthreads();
    if (tid < NF) {
      float acc = db[tid];
#pragma unroll 1
      for (int f = 0; f < F; ++f) acc += csave[f] * dw[f * NF + tid];
      out[b * NF + tid] = acc;
    }
  }
}

extern "C" void kernel_launch(void* const* d_in, const int* in_sizes, int n_in,
                              void* d_out, int out_size, void* d_ws, size_t ws_size,
                              hipStream_t stream) {
  const float* x   = (const float*)d_in[0];
  const float* w0  = (const float*)d_in[1];
  const float* b0  = (const float*)d_in[2];
  const float* w1  = (const float*)d_in[3];
  const float* b1  = (const float*)d_in[4];
  const float* w2  = (const float*)d_in[5];
  const float* b2  = (const float*)d_in[6];
  const float* Wx0 = (const float*)d_in[7];
  const float* Wh0 = (const float*)d_in[8];
  const float* bl0 = (const float*)d_in[9];
  const float* Wx1 = (const float*)d_in[10];
  const float* Wh1 = (const float*)d_in[11];
  const float* bl1 = (const float*)d_in[12];
  const float* dw  = (const float*)d_in[13];
  const float* db  = (const float*)d_in[14];
  float* out = (float*)d_out;

  char* ws = (char*)d_ws;
  float*    cv    = (float*)(ws + CV_OFF);
  float*    ring  = (float*)(ws + RING_OFF);
  uint32_t* flags = (uint32_t*)(ws + FLAGS_OFF);

  hipMemsetAsync(flags, 0, 16384, stream);
  conv_fused<<<dim3(4096), dim3(256), 0, stream>>>(x, w0, b0, w1, b1, w2, b2, cv);
  lstm_scan<<<dim3(128), dim3(256), 0, stream>>>(cv, ring, flags,
                                                 Wx0, Wh0, bl0, Wx1, Wh1, bl1,
                                                 dw, db, out);
}